// Round 1
// baseline (794.497 us; speedup 1.0000x reference)
//
#include <hip/hip_runtime.h>
#include <stdint.h>

#define HDIM 128
#define NGRID 262144
#define NMESH 40962
#define NEDGE 524288

typedef __attribute__((ext_vector_type(8))) short short8;
typedef __attribute__((ext_vector_type(4))) float f32x4;

__device__ __forceinline__ unsigned short f2bf(float f) {
  union { float f; uint32_t u; } v; v.f = f;
  uint32_t u = v.u;
  u += 0x7fffu + ((u >> 16) & 1u);
  return (unsigned short)(u >> 16);
}
__device__ __forceinline__ float bf2f(unsigned short h) {
  union { uint32_t u; float f; } v; v.u = ((uint32_t)h) << 16;
  return v.f;
}

// ---------------- pack weights: fp32 [K][128] -> bf16 transposed [128][K] ----------------
__global__ void pack_weights(const float* __restrict__ eW1, const float* __restrict__ eW2,
                             const float* __restrict__ nW1, const float* __restrict__ nW2,
                             unsigned short* __restrict__ ws)
{
  int i = blockIdx.x * 256 + threadIdx.x;
  unsigned short* eW1T = ws;           // [128][384]
  unsigned short* eW2T = ws + 49152;   // [128][128]
  unsigned short* nW1T = ws + 65536;   // [128][256]
  unsigned short* nW2T = ws + 98304;   // [128][128]
  if (i < 49152) {
    int c = i / 384, k = i % 384;
    eW1T[i] = f2bf(eW1[(size_t)k * 128 + c]);
  } else if (i < 65536) {
    int j = i - 49152; int c = j / 128, k = j % 128;
    eW2T[j] = f2bf(eW2[(size_t)k * 128 + c]);
  } else if (i < 98304) {
    int j = i - 65536; int c = j / 256, k = j % 256;
    nW1T[j] = f2bf(nW1[(size_t)k * 128 + c]);
  } else if (i < 114688) {
    int j = i - 98304; int c = j / 128, k = j % 128;
    nW2T[j] = f2bf(nW2[(size_t)k * 128 + c]);
  }
}

// ---------------- edge kernel: MLP+LN+residual, atomic scatter into agg(=d_out) ----------------
__global__ __launch_bounds__(256)
void edge_kernel(const float* __restrict__ ef, const float* __restrict__ gridf,
                 const float* __restrict__ mesh,
                 const unsigned short* __restrict__ W1T, const unsigned short* __restrict__ W2T,
                 const float* __restrict__ b1, const float* __restrict__ b2,
                 const float* __restrict__ lng, const float* __restrict__ lnb,
                 const int* __restrict__ src, const int* __restrict__ dst,
                 float* __restrict__ agg)
{
  __shared__ __align__(16) unsigned short xe[64][392];   // [edge][3*128 + pad8]
  __shared__ __align__(16) unsigned short h1s[64][136];  // [edge][128 + pad8]
  __shared__ __align__(16) unsigned short wt[128][40];   // [col][32k + pad8]
  __shared__ int sidx[64];
  __shared__ int didx[64];

  const int tid = threadIdx.x;
  const int wave = tid >> 6;
  const int lane = tid & 63;
  const int l16 = lane & 15;
  const int g4 = lane >> 4;
  const int e0 = blockIdx.x * 64;

  if (tid < 64) sidx[tid] = src[e0 + tid];
  else if (tid < 128) didx[tid - 64] = dst[e0 + tid - 64];
  __syncthreads();

  // gather + fp32->bf16: 192 row-copies (64 edges x {mesh(src), grid(dst), ef})
  {
    const int l32 = lane & 31;
    const int sub = lane >> 5;
    for (int i = 0; i < 24; ++i) {
      int rc = ((wave * 24 + i) << 1) | sub;   // 0..191
      int part = rc >> 6;
      int e = rc & 63;
      const float* base;
      if (part == 0)      base = mesh  + (size_t)sidx[e] * HDIM;
      else if (part == 1) base = gridf + (size_t)didx[e] * HDIM;
      else                base = ef    + (size_t)(e0 + e) * HDIM;
      float4 v = reinterpret_cast<const float4*>(base)[l32];
      ushort4 o;
      o.x = f2bf(v.x); o.y = f2bf(v.y); o.z = f2bf(v.z); o.w = f2bf(v.w);
      *reinterpret_cast<ushort4*>(&xe[e][part * 128 + l32 * 4]) = o;
    }
  }
  __syncthreads();

  const int arow = wave * 16 + l16;
  const int stg_r = tid >> 1, stg_h = tid & 1;

  // ---- GEMM1: h1 = silu(xe @ W1 + b1), K=384 ----
  f32x4 acc[8];
  #pragma unroll
  for (int c = 0; c < 8; ++c) acc[c] = (f32x4){0.f, 0.f, 0.f, 0.f};

  for (int ks = 0; ks < 12; ++ks) {
    {
      const unsigned short* gp = W1T + (size_t)stg_r * 384 + ks * 32 + stg_h * 16;
      uint4 a0 = *reinterpret_cast<const uint4*>(gp);
      uint4 a1 = *reinterpret_cast<const uint4*>(gp + 8);
      unsigned short* dp = &wt[stg_r][stg_h * 16];
      *reinterpret_cast<uint4*>(dp) = a0;
      *reinterpret_cast<uint4*>(dp + 8) = a1;
    }
    __syncthreads();
    short8 a = *reinterpret_cast<const short8*>(&xe[arow][ks * 32 + g4 * 8]);
    #pragma unroll
    for (int c = 0; c < 8; ++c) {
      short8 b = *reinterpret_cast<const short8*>(&wt[c * 16 + l16][g4 * 8]);
      acc[c] = __builtin_amdgcn_mfma_f32_16x16x32_bf16(a, b, acc[c], 0, 0, 0);
    }
    __syncthreads();
  }

  // silu + store h1 as bf16
  #pragma unroll
  for (int c = 0; c < 8; ++c) {
    int col = c * 16 + l16;
    float bb = b1[col];
    #pragma unroll
    for (int r = 0; r < 4; ++r) {
      float x = acc[c][r] + bb;
      float s = x / (1.f + __expf(-x));
      h1s[wave * 16 + g4 * 4 + r][col] = f2bf(s);
    }
  }
  __syncthreads();

  // ---- GEMM2: he = h1 @ W2 + b2, K=128 ----
  f32x4 acc2[8];
  #pragma unroll
  for (int c = 0; c < 8; ++c) acc2[c] = (f32x4){0.f, 0.f, 0.f, 0.f};

  for (int ks = 0; ks < 4; ++ks) {
    {
      const unsigned short* gp = W2T + (size_t)stg_r * 128 + ks * 32 + stg_h * 16;
      uint4 a0 = *reinterpret_cast<const uint4*>(gp);
      uint4 a1 = *reinterpret_cast<const uint4*>(gp + 8);
      unsigned short* dp = &wt[stg_r][stg_h * 16];
      *reinterpret_cast<uint4*>(dp) = a0;
      *reinterpret_cast<uint4*>(dp + 8) = a1;
    }
    __syncthreads();
    short8 a = *reinterpret_cast<const short8*>(&h1s[arow][ks * 32 + g4 * 8]);
    #pragma unroll
    for (int c = 0; c < 8; ++c) {
      short8 b = *reinterpret_cast<const short8*>(&wt[c * 16 + l16][g4 * 8]);
      acc2[c] = __builtin_amdgcn_mfma_f32_16x16x32_bf16(a, b, acc2[c], 0, 0, 0);
    }
    __syncthreads();
  }

  // ---- +b2, LayerNorm over 128 cols, +residual(ef), atomic scatter ----
  float vs[4] = {0.f, 0.f, 0.f, 0.f};
  float vq[4] = {0.f, 0.f, 0.f, 0.f};
  #pragma unroll
  for (int c = 0; c < 8; ++c) {
    float bb = b2[c * 16 + l16];
    #pragma unroll
    for (int r = 0; r < 4; ++r) {
      float x = acc2[c][r] + bb;
      acc2[c][r] = x;
      vs[r] += x;
      vq[r] += x * x;
    }
  }
  #pragma unroll
  for (int m = 1; m < 16; m <<= 1) {
    #pragma unroll
    for (int r = 0; r < 4; ++r) {
      vs[r] += __shfl_xor(vs[r], m);
      vq[r] += __shfl_xor(vq[r], m);
    }
  }
  float mean[4], rstd[4];
  #pragma unroll
  for (int r = 0; r < 4; ++r) {
    mean[r] = vs[r] * (1.f / 128.f);
    float var = vq[r] * (1.f / 128.f) - mean[r] * mean[r];
    rstd[r] = rsqrtf(var + 1e-5f);
  }
  #pragma unroll
  for (int c = 0; c < 8; ++c) {
    int col = c * 16 + l16;
    float gg = lng[col], bb = lnb[col];
    #pragma unroll
    for (int r = 0; r < 4; ++r) {
      int row = wave * 16 + g4 * 4 + r;
      float y = (acc2[c][r] - mean[r]) * rstd[r] * gg + bb;
      float e = bf2f(xe[row][256 + col]) + y;
      atomicAdd(&agg[(size_t)didx[row] * HDIM + col], e);
    }
  }
}

// ---------------- node kernel: xn=[grid|agg] MLP + LN + residual, in-place on d_out ----------------
__global__ __launch_bounds__(256)
void node_kernel(const float* __restrict__ gridf,
                 const unsigned short* __restrict__ W1T, const unsigned short* __restrict__ W2T,
                 const float* __restrict__ b1, const float* __restrict__ b2,
                 const float* __restrict__ lng, const float* __restrict__ lnb,
                 float* __restrict__ out)
{
  __shared__ __align__(16) unsigned short xn[64][264];   // [node][2*128 + pad8]
  __shared__ __align__(16) unsigned short h1s[64][136];
  __shared__ __align__(16) unsigned short wt[128][40];

  const int tid = threadIdx.x;
  const int wave = tid >> 6;
  const int lane = tid & 63;
  const int l16 = lane & 15;
  const int g4 = lane >> 4;
  const int n0 = blockIdx.x * 64;

  {
    const int l32 = lane & 31;
    const int sub = lane >> 5;
    for (int i = 0; i < 16; ++i) {
      int rc = ((wave * 16 + i) << 1) | sub;   // 0..127
      int part = rc >> 6;
      int e = rc & 63;
      const float* base = (part == 0) ? gridf + (size_t)(n0 + e) * HDIM
                                      : out   + (size_t)(n0 + e) * HDIM;
      float4 v = reinterpret_cast<const float4*>(base)[l32];
      ushort4 o;
      o.x = f2bf(v.x); o.y = f2bf(v.y); o.z = f2bf(v.z); o.w = f2bf(v.w);
      *reinterpret_cast<ushort4*>(&xn[e][part * 128 + l32 * 4]) = o;
    }
  }
  __syncthreads();

  const int arow = wave * 16 + l16;
  const int stg_r = tid >> 1, stg_h = tid & 1;

  // ---- GEMM1: K=256 ----
  f32x4 acc[8];
  #pragma unroll
  for (int c = 0; c < 8; ++c) acc[c] = (f32x4){0.f, 0.f, 0.f, 0.f};

  for (int ks = 0; ks < 8; ++ks) {
    {
      const unsigned short* gp = W1T + (size_t)stg_r * 256 + ks * 32 + stg_h * 16;
      uint4 a0 = *reinterpret_cast<const uint4*>(gp);
      uint4 a1 = *reinterpret_cast<const uint4*>(gp + 8);
      unsigned short* dp = &wt[stg_r][stg_h * 16];
      *reinterpret_cast<uint4*>(dp) = a0;
      *reinterpret_cast<uint4*>(dp + 8) = a1;
    }
    __syncthreads();
    short8 a = *reinterpret_cast<const short8*>(&xn[arow][ks * 32 + g4 * 8]);
    #pragma unroll
    for (int c = 0; c < 8; ++c) {
      short8 b = *reinterpret_cast<const short8*>(&wt[c * 16 + l16][g4 * 8]);
      acc[c] = __builtin_amdgcn_mfma_f32_16x16x32_bf16(a, b, acc[c], 0, 0, 0);
    }
    __syncthreads();
  }

  #pragma unroll
  for (int c = 0; c < 8; ++c) {
    int col = c * 16 + l16;
    float bb = b1[col];
    #pragma unroll
    for (int r = 0; r < 4; ++r) {
      float x = acc[c][r] + bb;
      float s = x / (1.f + __expf(-x));
      h1s[wave * 16 + g4 * 4 + r][col] = f2bf(s);
    }
  }
  __syncthreads();

  // ---- GEMM2: K=128 ----
  f32x4 acc2[8];
  #pragma unroll
  for (int c = 0; c < 8; ++c) acc2[c] = (f32x4){0.f, 0.f, 0.f, 0.f};

  for (int ks = 0; ks < 4; ++ks) {
    {
      const unsigned short* gp = W2T + (size_t)stg_r * 128 + ks * 32 + stg_h * 16;
      uint4 a0 = *reinterpret_cast<const uint4*>(gp);
      uint4 a1 = *reinterpret_cast<const uint4*>(gp + 8);
      unsigned short* dp = &wt[stg_r][stg_h * 16];
      *reinterpret_cast<uint4*>(dp) = a0;
      *reinterpret_cast<uint4*>(dp + 8) = a1;
    }
    __syncthreads();
    short8 a = *reinterpret_cast<const short8*>(&h1s[arow][ks * 32 + g4 * 8]);
    #pragma unroll
    for (int c = 0; c < 8; ++c) {
      short8 b = *reinterpret_cast<const short8*>(&wt[c * 16 + l16][g4 * 8]);
      acc2[c] = __builtin_amdgcn_mfma_f32_16x16x32_bf16(a, b, acc2[c], 0, 0, 0);
    }
    __syncthreads();
  }

  // ---- +b2, LN, + fp32 grid residual, store ----
  float vs[4] = {0.f, 0.f, 0.f, 0.f};
  float vq[4] = {0.f, 0.f, 0.f, 0.f};
  #pragma unroll
  for (int c = 0; c < 8; ++c) {
    float bb = b2[c * 16 + l16];
    #pragma unroll
    for (int r = 0; r < 4; ++r) {
      float x = acc2[c][r] + bb;
      acc2[c][r] = x;
      vs[r] += x;
      vq[r] += x * x;
    }
  }
  #pragma unroll
  for (int m = 1; m < 16; m <<= 1) {
    #pragma unroll
    for (int r = 0; r < 4; ++r) {
      vs[r] += __shfl_xor(vs[r], m);
      vq[r] += __shfl_xor(vq[r], m);
    }
  }
  float mean[4], rstd[4];
  #pragma unroll
  for (int r = 0; r < 4; ++r) {
    mean[r] = vs[r] * (1.f / 128.f);
    float var = vq[r] * (1.f / 128.f) - mean[r] * mean[r];
    rstd[r] = rsqrtf(var + 1e-5f);
  }
  #pragma unroll
  for (int c = 0; c < 8; ++c) {
    int col = c * 16 + l16;
    float gg = lng[col], bb = lnb[col];
    #pragma unroll
    for (int r = 0; r < 4; ++r) {
      int row = wave * 16 + g4 * 4 + r;
      size_t idx = (size_t)(n0 + row) * HDIM + col;
      float y = (acc2[c][r] - mean[r]) * rstd[r] * gg + bb;
      out[idx] = gridf[idx] + y;
    }
  }
}

extern "C" void kernel_launch(void* const* d_in, const int* in_sizes, int n_in,
                              void* d_out, int out_size, void* d_ws, size_t ws_size,
                              hipStream_t stream)
{
  (void)in_sizes; (void)n_in; (void)out_size; (void)ws_size;
  const float* ef   = (const float*)d_in[0];
  const float* grid = (const float*)d_in[1];
  const float* mesh = (const float*)d_in[2];
  const float* eW1  = (const float*)d_in[3];
  const float* eb1  = (const float*)d_in[4];
  const float* eW2  = (const float*)d_in[5];
  const float* eb2  = (const float*)d_in[6];
  const float* elng = (const float*)d_in[7];
  const float* elnb = (const float*)d_in[8];
  const float* nW1  = (const float*)d_in[9];
  const float* nb1  = (const float*)d_in[10];
  const float* nW2  = (const float*)d_in[11];
  const float* nb2  = (const float*)d_in[12];
  const float* nlng = (const float*)d_in[13];
  const float* nlnb = (const float*)d_in[14];
  const int* src    = (const int*)d_in[15];
  const int* dst    = (const int*)d_in[16];
  float* out = (float*)d_out;
  unsigned short* ws = (unsigned short*)d_ws;

  hipMemsetAsync(out, 0, (size_t)NGRID * HDIM * sizeof(float), stream);
  pack_weights<<<448, 256, 0, stream>>>(eW1, eW2, nW1, nW2, ws);
  edge_kernel<<<NEDGE / 64, 256, 0, stream>>>(ef, grid, mesh,
      ws, ws + 49152, eb1, eb2, elng, elnb, src, dst, out);
  node_kernel<<<NGRID / 64, 256, 0, stream>>>(grid,
      ws + 65536, ws + 98304, nb1, nb2, nlng, nlnb, out);
}